// Round 1
// baseline (92.482 us; speedup 1.0000x reference)
//
#include <hip/hip_runtime.h>

// Problem constants (fixed by the bench): B=16, N=2048, S=SO=12, K=32.
// out[b,i,k,s] = softmax_k( leaky_relu( x[b,i,:]·w_src + x[b,idx,:]·w_dst ) ) * x[b,idx[b,i,k],s]
// where w_src = W @ a[:12], w_dst = W @ a[12:]. Fully fused: the neighbor row
// needed for e_dst is the same row written to the output, so e_dst costs 0 extra bytes.

#define GAT_N 2048
#define GAT_ALPHA 0.5f

__global__ __launch_bounds__(256) void gat_fused(
    const float* __restrict__ x,    // [B*N, 12]  (input_data)
    const float* __restrict__ W,    // [12,12]
    const float* __restrict__ a,    // [24]
    const int*   __restrict__ idx,  // [B*N, 32]
    float*       __restrict__ out)  // [B*N, 32, 12]
{
    __shared__ float wvec[24];      // [0..11] = w_src, [12..23] = w_dst
    const int tid = threadIdx.x;

    // w_src[s] = sum_t W[s][t]*a[t] ; w_dst[s] = sum_t W[s][t]*a[12+t]
    if (tid < 24) {
        const int s = tid % 12;
        const float* av = a + (tid < 12 ? 0 : 12);
        float acc = 0.f;
        #pragma unroll
        for (int t = 0; t < 12; ++t) acc += W[s * 12 + t] * av[t];
        wvec[tid] = acc;
    }
    __syncthreads();

    const int pair = blockIdx.x * 8 + (tid >> 5);   // (b*N + i), 8 per block
    const int k    = tid & 31;                       // neighbor slot

    // --- e_src from own row (same addr across 32 lanes -> broadcast loads) ---
    const float4* rowi = (const float4*)(x + (size_t)pair * 12);
    const float4 i0 = rowi[0], i1 = rowi[1], i2 = rowi[2];
    const float e_src =
        i0.x*wvec[0] + i0.y*wvec[1] + i0.z*wvec[2]  + i0.w*wvec[3] +
        i1.x*wvec[4] + i1.y*wvec[5] + i1.z*wvec[6]  + i1.w*wvec[7] +
        i2.x*wvec[8] + i2.y*wvec[9] + i2.z*wvec[10] + i2.w*wvec[11];

    // --- gather neighbor row; e_dst from the same data we must output anyway ---
    const int j = idx[(size_t)pair * 32 + k];
    const int nbr = (pair & ~(GAT_N - 1)) + j;       // b*N + j  (N is pow2)
    const float4* rowj = (const float4*)(x + (size_t)nbr * 12);
    const float4 n0 = rowj[0], n1 = rowj[1], n2 = rowj[2];
    const float e_dst =
        n0.x*wvec[12] + n0.y*wvec[13] + n0.z*wvec[14] + n0.w*wvec[15] +
        n1.x*wvec[16] + n1.y*wvec[17] + n1.z*wvec[18] + n1.w*wvec[19] +
        n2.x*wvec[20] + n2.y*wvec[21] + n2.z*wvec[22] + n2.w*wvec[23];

    // --- leaky_relu + softmax over the 32 lanes of this half-wave ---
    float sc = e_src + e_dst;
    sc = sc > 0.f ? sc : GAT_ALPHA * sc;

    float m = sc;
    #pragma unroll
    for (int off = 16; off; off >>= 1) m = fmaxf(m, __shfl_xor(m, off, 32));
    const float ex = __expf(sc - m);
    float sum = ex;
    #pragma unroll
    for (int off = 16; off; off >>= 1) sum += __shfl_xor(sum, off, 32);
    const float att = ex / sum;

    // --- write att * neigh : 12 consecutive floats per lane, 3x dwordx4 ---
    float4* o = (float4*)(out + (size_t)pair * 384 + k * 12);
    o[0] = make_float4(att * n0.x, att * n0.y, att * n0.z, att * n0.w);
    o[1] = make_float4(att * n1.x, att * n1.y, att * n1.z, att * n1.w);
    o[2] = make_float4(att * n2.x, att * n2.y, att * n2.z, att * n2.w);
}

extern "C" void kernel_launch(void* const* d_in, const int* in_sizes, int n_in,
                              void* d_out, int out_size, void* d_ws, size_t ws_size,
                              hipStream_t stream) {
    // setup_inputs order: fushed_features (unused), input_data, W, a, idx
    const float* x   = (const float*)d_in[1];
    const float* W   = (const float*)d_in[2];
    const float* a   = (const float*)d_in[3];
    const int*   idx = (const int*)d_in[4];
    float* out = (float*)d_out;

    const int pairs = in_sizes[1] / 12;          // B*N = 32768
    const int blocks = pairs / 8;                // 8 pairs per 256-thread block
    gat_fused<<<blocks, 256, 0, stream>>>(x, W, a, idx, out);
}

// Round 2
// 91.475 us; speedup vs baseline: 1.0110x; 1.0110x over previous
//
#include <hip/hip_runtime.h>

// B=16, N=2048, S=SO=12, K=32.
// out[b,i,k,s] = softmax_k( leaky_relu( x[b,i,:]·w_src + x[b,j,:]·w_dst ) ) * x[b,j,s],  j=idx[b,i,k]
// w_src = W @ a[:12], w_dst = W @ a[12:].
// Half-wave (32 lanes) per (b,i) pair; neighbor row loaded once serves both
// e_dst and the output product. Output staged through LDS so global stores are
// fully coalesced dwordx4 (the naive per-lane layout is 16B-at-48B-stride scatter).

#define GAT_N 2048
#define GAT_ALPHA 0.5f
#define PPB 8   // pairs per 256-thread block

__global__ __launch_bounds__(256) void gat_fused(
    const float* __restrict__ x,    // [B*N, 12]
    const float* __restrict__ W,    // [12,12]
    const float* __restrict__ a,    // [24]
    const int*   __restrict__ idx,  // [B*N, 32]
    float*       __restrict__ out)  // [B*N, 32, 12]
{
    __shared__ float wvec[24];              // w_src | w_dst
    __shared__ float stage[PPB * 384];      // 12 KB output staging
    const int tid = threadIdx.x;

    if (tid < 24) {
        const int s = tid % 12;
        const float* av = a + (tid < 12 ? 0 : 12);
        float acc = 0.f;
        #pragma unroll
        for (int t = 0; t < 12; ++t) acc += W[s * 12 + t] * av[t];
        wvec[tid] = acc;
    }
    __syncthreads();

    const int p    = tid >> 5;                       // pair slot in block
    const int pair = blockIdx.x * PPB + p;           // b*N + i
    const int k    = tid & 31;                       // neighbor slot

    // e_src: all 32 lanes load the same row -> broadcast
    const float4* rowi = (const float4*)(x + (size_t)pair * 12);
    const float4 i0 = rowi[0], i1 = rowi[1], i2 = rowi[2];
    const float e_src =
        i0.x*wvec[0] + i0.y*wvec[1] + i0.z*wvec[2]  + i0.w*wvec[3] +
        i1.x*wvec[4] + i1.y*wvec[5] + i1.z*wvec[6]  + i1.w*wvec[7] +
        i2.x*wvec[8] + i2.y*wvec[9] + i2.z*wvec[10] + i2.w*wvec[11];

    // gather neighbor row (inherently scattered; ~96 KB/batch lives in L2)
    const int j   = idx[(size_t)pair * 32 + k];
    const int nbr = (pair & ~(GAT_N - 1)) + j;       // b*N + j
    const float4* rowj = (const float4*)(x + (size_t)nbr * 12);
    const float4 n0 = rowj[0], n1 = rowj[1], n2 = rowj[2];
    const float e_dst =
        n0.x*wvec[12] + n0.y*wvec[13] + n0.z*wvec[14] + n0.w*wvec[15] +
        n1.x*wvec[16] + n1.y*wvec[17] + n1.z*wvec[18] + n1.w*wvec[19] +
        n2.x*wvec[20] + n2.y*wvec[21] + n2.z*wvec[22] + n2.w*wvec[23];

    // leaky_relu + softmax over 32 lanes (half-wave segment)
    float sc = e_src + e_dst;
    sc = sc > 0.f ? sc : GAT_ALPHA * sc;
    float m = sc;
    #pragma unroll
    for (int off = 16; off; off >>= 1) m = fmaxf(m, __shfl_xor(m, off, 32));
    const float ex = __expf(sc - m);
    float sum = ex;
    #pragma unroll
    for (int off = 16; off; off >>= 1) sum += __shfl_xor(sum, off, 32);
    const float att = ex / sum;

    // stage att * neigh into LDS (3x ds_write_b128 per lane)
    float4* st = (float4*)(stage + p * 384 + k * 12);
    st[0] = make_float4(att * n0.x, att * n0.y, att * n0.z, att * n0.w);
    st[1] = make_float4(att * n1.x, att * n1.y, att * n1.z, att * n1.w);
    st[2] = make_float4(att * n2.x, att * n2.y, att * n2.z, att * n2.w);
    __syncthreads();

    // block-wide coalesced flush: 8*384 floats = 768 float4, 3 per thread
    const float4* sm4 = (const float4*)stage;
    float4* o4 = (float4*)(out + (size_t)blockIdx.x * PPB * 384);
    #pragma unroll
    for (int r = 0; r < 3; ++r) o4[tid + 256 * r] = sm4[tid + 256 * r];
}

extern "C" void kernel_launch(void* const* d_in, const int* in_sizes, int n_in,
                              void* d_out, int out_size, void* d_ws, size_t ws_size,
                              hipStream_t stream) {
    // inputs: fushed_features (unused), input_data, W, a, idx
    const float* x   = (const float*)d_in[1];
    const float* W   = (const float*)d_in[2];
    const float* a   = (const float*)d_in[3];
    const int*   idx = (const int*)d_in[4];
    float* out = (float*)d_out;

    const int pairs  = in_sizes[1] / 12;   // B*N = 32768
    const int blocks = pairs / PPB;        // 4096
    gat_fused<<<blocks, 256, 0, stream>>>(x, W, a, idx, out);
}